// Round 4
// baseline (2093.312 us; speedup 1.0000x reference)
//
#include <hip/hip_runtime.h>
#include <cmath>

#define HIDC   128
#define NHEADS 8
#define DHEAD  16
#define LAYERS 4
#define IN_C   64
#define OUT_C  64

__device__ __forceinline__ float gelu_f(float x) {
    return 0.5f * x * (1.0f + erff(x * 0.70710678118654752f));
}

// ------------------------------ CSR build ------------------------------
__global__ void count_deg_k(const int* __restrict__ dst, int* __restrict__ cnt, int E) {
    int i = blockIdx.x * blockDim.x + threadIdx.x;
    if (i < E) atomicAdd(&cnt[dst[i]], 1);
}

__global__ __launch_bounds__(1024)
void scan_k(const int* __restrict__ cnt, int* __restrict__ rowptr, int n) {
    __shared__ int partials[1024];
    int tid = threadIdx.x;
    int per = (n + 1023) / 1024;
    int start = tid * per;
    int end = start + per; if (end > n) end = n;
    int s = 0;
    for (int i = start; i < end; ++i) s += cnt[i];
    partials[tid] = s;
    __syncthreads();
    for (int off = 1; off < 1024; off <<= 1) {
        int v = (tid >= off) ? partials[tid - off] : 0;
        __syncthreads();
        partials[tid] += v;
        __syncthreads();
    }
    int run = (tid == 0) ? 0 : partials[tid - 1];
    for (int i = start; i < end; ++i) { rowptr[i] = run; run += cnt[i]; }
    if (tid == 1023) rowptr[n] = partials[1023];
}

__global__ void scatter_k(const int* __restrict__ src, const int* __restrict__ dst,
                          const int* __restrict__ rowptr, int* __restrict__ cnt,
                          int* __restrict__ csrc, int E) {
    int i = blockIdx.x * blockDim.x + threadIdx.x;
    if (i < E) {
        int d = dst[i];
        int pos = rowptr[d] + atomicAdd(&cnt[d], 1);
        csrc[pos] = src[i];
    }
}

// ------------------------------ GEMM: C = A @ W^T + bias (+act)(+resid) ----
// A: [M,K] row-major. W: [NC,K] row-major. C: [M,NC].
// ACT: 0 = none, 1 = gelu.  RES: add resid[M,NC].
#define BM 64
#define BN 64
#define BKK 32

template<int ACT, bool RES>
__global__ __launch_bounds__(256)
void gemm_k(const float* __restrict__ A, const float* __restrict__ W,
            const float* __restrict__ bias, const float* __restrict__ resid,
            float* __restrict__ C, int M, int NC, int K) {
    __shared__ float As[BKK][BM + 4];
    __shared__ float Ws[BKK][BN + 4];
    int tid = threadIdx.x;
    int row0 = blockIdx.y * BM;
    int col0 = blockIdx.x * BN;
    int ty = tid >> 4, tx = tid & 15;

    float acc[4][4];
#pragma unroll
    for (int i = 0; i < 4; ++i)
#pragma unroll
        for (int j = 0; j < 4; ++j) acc[i][j] = 0.f;

    int lr = tid >> 3;          // 0..31
    int lc = (tid & 7) * 4;     // 0..28

    for (int k0 = 0; k0 < K; k0 += BKK) {
        // A tile (transposed into LDS), rows may exceed M
#pragma unroll
        for (int rr = lr; rr < BM; rr += 32) {
            int grow = row0 + rr;
            float4 val = make_float4(0.f, 0.f, 0.f, 0.f);
            if (grow < M) val = *(const float4*)(A + (size_t)grow * K + k0 + lc);
            As[lc + 0][rr] = val.x;
            As[lc + 1][rr] = val.y;
            As[lc + 2][rr] = val.z;
            As[lc + 3][rr] = val.w;
        }
        // W tile (NC is always a multiple of 64 here)
#pragma unroll
        for (int rr = lr; rr < BN; rr += 32) {
            int grow = col0 + rr;
            float4 val = *(const float4*)(W + (size_t)grow * K + k0 + lc);
            Ws[lc + 0][rr] = val.x;
            Ws[lc + 1][rr] = val.y;
            Ws[lc + 2][rr] = val.z;
            Ws[lc + 3][rr] = val.w;
        }
        __syncthreads();
#pragma unroll
        for (int k = 0; k < BKK; ++k) {
            float a[4], b[4];
            *(float4*)a = *(const float4*)&As[k][ty * 4];
            *(float4*)b = *(const float4*)&Ws[k][tx * 4];
#pragma unroll
            for (int i = 0; i < 4; ++i)
#pragma unroll
                for (int j = 0; j < 4; ++j) acc[i][j] += a[i] * b[j];
        }
        __syncthreads();
    }

    float4 bv = *(const float4*)(bias + col0 + tx * 4);
#pragma unroll
    for (int i = 0; i < 4; ++i) {
        int grow = row0 + ty * 4 + i;
        if (grow >= M) continue;
        float4 o;
        o.x = acc[i][0] + bv.x;
        o.y = acc[i][1] + bv.y;
        o.z = acc[i][2] + bv.z;
        o.w = acc[i][3] + bv.w;
        if (ACT == 1) { o.x = gelu_f(o.x); o.y = gelu_f(o.y); o.z = gelu_f(o.z); o.w = gelu_f(o.w); }
        size_t base = (size_t)grow * NC + col0 + tx * 4;
        if (RES) {
            float4 r = *(const float4*)(resid + base);
            o.x += r.x; o.y += r.y; o.z += r.z; o.w += r.w;
        }
        *(float4*)(C + base) = o;
    }
}

// ------------------------------ Attention: one wave per dst node -----------
__global__ __launch_bounds__(256)
void attn_k(const float* __restrict__ Q, const float* __restrict__ K,
            const float* __restrict__ V, const int* __restrict__ rowptr,
            const int* __restrict__ csrc, float* __restrict__ out, int n) {
    int wave = (int)((blockIdx.x * (size_t)blockDim.x + threadIdx.x) >> 6);
    int lane = threadIdx.x & 63;
    if (wave >= n) return;
    size_t base = (size_t)wave * HIDC + lane * 2;
    float2 q = *(const float2*)(Q + base);
    float m = -INFINITY, ssum = 0.f;
    float accx = 0.f, accy = 0.f;
    int e0 = rowptr[wave], e1 = rowptr[wave + 1];
    for (int e = e0; e < e1; ++e) {
        int s = csrc[e];
        size_t sb = (size_t)s * HIDC + lane * 2;
        float2 k2 = *(const float2*)(K + sb);
        float2 v2 = *(const float2*)(V + sb);
        float d = q.x * k2.x + q.y * k2.y;
        d += __shfl_xor(d, 1);
        d += __shfl_xor(d, 2);
        d += __shfl_xor(d, 4);          // sum over the 8 lanes of this head
        float alpha = d * 0.25f;        // 1/sqrt(16)
        float mnew = fmaxf(m, alpha);
        float corr = expf(m - mnew);    // exp(-inf)=0 on first edge
        float w = expf(alpha - mnew);
        ssum = ssum * corr + w;
        accx = accx * corr + w * v2.x;
        accy = accy * corr + w * v2.y;
        m = mnew;
    }
    float inv = 1.f / (ssum + 1e-16f);
    float2 o = make_float2(accx * inv, accy * inv);
    *(float2*)(out + base) = o;
}

// --------------- beta gate + residual + layernorm: one wave per node -------
// NOTE: attn and out may alias (same buffer) — each thread reads/writes only
// its own element, reads happen before the write. Race-free in-place.
__global__ __launch_bounds__(256)
void beta_ln_k(const float* __restrict__ attn, const float* __restrict__ xr,
               const float* __restrict__ res, const float* __restrict__ Wb,
               const float* __restrict__ g, const float* __restrict__ b,
               float* __restrict__ out, int n) {
    int wave = (int)((blockIdx.x * (size_t)blockDim.x + threadIdx.x) >> 6);
    int lane = threadIdx.x & 63;
    if (wave >= n) return;
    size_t base = (size_t)wave * HIDC + lane * 2;
    int c = lane * 2;
    float2 o = *(const float2*)(attn + base);
    float2 r = *(const float2*)(xr + base);
    float2 wb0 = *(const float2*)(Wb + c);
    float2 wb1 = *(const float2*)(Wb + HIDC + c);
    float2 wb2 = *(const float2*)(Wb + 2 * HIDC + c);
    float part = o.x * wb0.x + o.y * wb0.y
               + r.x * wb1.x + r.y * wb1.y
               + (o.x - r.x) * wb2.x + (o.y - r.y) * wb2.y;
#pragma unroll
    for (int mk = 1; mk < 64; mk <<= 1) part += __shfl_xor(part, mk);
    float beta = 1.f / (1.f + expf(-part));
    float2 rs = *(const float2*)(res + base);
    float tx = beta * r.x + (1.f - beta) * o.x + rs.x;
    float ty = beta * r.y + (1.f - beta) * o.y + rs.y;
    float sum = tx + ty;
#pragma unroll
    for (int mk = 1; mk < 64; mk <<= 1) sum += __shfl_xor(sum, mk);
    float mean = sum * (1.f / 128.f);
    float dx = tx - mean, dy = ty - mean;
    float vs = dx * dx + dy * dy;
#pragma unroll
    for (int mk = 1; mk < 64; mk <<= 1) vs += __shfl_xor(vs, mk);
    float rstd = 1.f / sqrtf(vs * (1.f / 128.f) + 1e-5f);
    float2 gg = *(const float2*)(g + c);
    float2 bb = *(const float2*)(b + c);
    float2 oo = make_float2(dx * rstd * gg.x + bb.x, dy * rstd * gg.y + bb.y);
    *(float2*)(out + base) = oo;
}

// ------------------------------ host launch ------------------------------
extern "C" void kernel_launch(void* const* d_in, const int* in_sizes, int n_in,
                              void* d_out, int out_size, void* d_ws, size_t ws_size,
                              hipStream_t stream) {
    const float* x    = (const float*)d_in[0];
    const int*   ei   = (const int*)d_in[1];      // int32 per harness contract
    const float* Wi   = (const float*)d_in[2];
    const float* bi   = (const float*)d_in[3];
    const float* Wq   = (const float*)d_in[4];
    const float* bq   = (const float*)d_in[5];
    const float* Wk   = (const float*)d_in[6];
    const float* bk   = (const float*)d_in[7];
    const float* Wv   = (const float*)d_in[8];
    const float* bv   = (const float*)d_in[9];
    const float* Ws_  = (const float*)d_in[10];
    const float* bs   = (const float*)d_in[11];
    const float* Wbeta= (const float*)d_in[12];
    const float* ln_g = (const float*)d_in[13];
    const float* ln_b = (const float*)d_in[14];
    const float* W1   = (const float*)d_in[15];
    const float* b1   = (const float*)d_in[16];
    const float* W2   = (const float*)d_in[17];
    const float* b2   = (const float*)d_in[18];
    const float* Wo   = (const float*)d_in[19];
    const float* bo   = (const float*)d_in[20];
    float* outp = (float*)d_out;

    const int Nn = in_sizes[0] / IN_C;   // 50000
    const int Ee = in_sizes[1] / 2;      // 600000
    const int* srcI = ei;
    const int* dstI = ei + Ee;

    // workspace layout (floats) — 6 * N*128 * 4B = 153.6 MB + ~2.8 MB ints
    float* ws = (float*)d_ws;
    size_t n128 = (size_t)Nn * HIDC;
    float* h    = ws;                 // [N,128] running hidden
    float* h2   = h   + n128;         // [N,128] post-LN hidden; also attn out
    float* qb   = h2  + n128;         // [N,128]
    float* kb   = qb  + n128;         // [N,128]
    float* vb   = kb  + n128;         // [N,128]
    float* sb   = vb  + n128;         // [N,128] (x_r)
    float* ab   = h2;                 // attention out aliases h2 (dead then)
    float* ffn  = qb;                 // [N,512] aliases q/k/v/s (dead by FFN)
    int* rowptr = (int*)(sb + n128);  // N+1
    int* cnt    = rowptr + (Nn + 1);  // N
    int* csrc   = cnt + Nn;           // E

    // ---- CSR build (edge_index constant, rebuilt each launch) ----
    hipMemsetAsync(cnt, 0, Nn * sizeof(int), stream);
    count_deg_k<<<(Ee + 255) / 256, 256, 0, stream>>>(dstI, cnt, Ee);
    scan_k<<<1, 1024, 0, stream>>>(cnt, rowptr, Nn);
    hipMemsetAsync(cnt, 0, Nn * sizeof(int), stream);
    scatter_k<<<(Ee + 255) / 256, 256, 0, stream>>>(srcI, dstI, rowptr, cnt, csrc, Ee);

    int mblk = (Nn + BM - 1) / BM;    // 782
    dim3 blk(256);

    // ---- input projection: h = gelu(x @ Wi^T + bi) ----
    gemm_k<1, false><<<dim3(HIDC / BN, mblk), blk, 0, stream>>>(x, Wi, bi, nullptr, h, Nn, HIDC, IN_C);

    int nwaveblk = (Nn + 3) / 4;      // 4 waves of 64 per 256-thread block

    for (int l = 0; l < LAYERS; ++l) {
        const float* Wq_l = Wq + (size_t)l * HIDC * HIDC;
        const float* Wk_l = Wk + (size_t)l * HIDC * HIDC;
        const float* Wv_l = Wv + (size_t)l * HIDC * HIDC;
        const float* Ws_l = Ws_ + (size_t)l * HIDC * HIDC;
        const float* bq_l = bq + (size_t)l * HIDC;
        const float* bk_l = bk + (size_t)l * HIDC;
        const float* bv_l = bv + (size_t)l * HIDC;
        const float* bs_l = bs + (size_t)l * HIDC;
        const float* Wb_l = Wbeta + (size_t)l * 3 * HIDC;
        const float* g_l  = ln_g + (size_t)l * HIDC;
        const float* b_l  = ln_b + (size_t)l * HIDC;
        const float* W1_l = W1 + (size_t)l * 4 * HIDC * HIDC;
        const float* b1_l = b1 + (size_t)l * 4 * HIDC;
        const float* W2_l = W2 + (size_t)l * HIDC * 4 * HIDC;
        const float* b2_l = b2 + (size_t)l * HIDC;

        dim3 g2(HIDC / BN, mblk);
        gemm_k<0, false><<<g2, blk, 0, stream>>>(h, Wq_l, bq_l, nullptr, qb, Nn, HIDC, HIDC);
        gemm_k<0, false><<<g2, blk, 0, stream>>>(h, Wk_l, bk_l, nullptr, kb, Nn, HIDC, HIDC);
        gemm_k<0, false><<<g2, blk, 0, stream>>>(h, Wv_l, bv_l, nullptr, vb, Nn, HIDC, HIDC);
        gemm_k<0, false><<<g2, blk, 0, stream>>>(h, Ws_l, bs_l, nullptr, sb, Nn, HIDC, HIDC);

        attn_k<<<nwaveblk, blk, 0, stream>>>(qb, kb, vb, rowptr, csrc, ab, Nn);

        beta_ln_k<<<nwaveblk, blk, 0, stream>>>(ab, sb, h, Wb_l, g_l, b_l, h2, Nn);

        // FFN: ffn = gelu(h2 @ W1^T + b1);  h = ffn @ W2^T + b2 + h2
        gemm_k<1, false><<<dim3(4 * HIDC / BN, mblk), blk, 0, stream>>>(h2, W1_l, b1_l, nullptr, ffn, Nn, 4 * HIDC, HIDC);
        gemm_k<0, true><<<dim3(HIDC / BN, mblk), blk, 0, stream>>>(ffn, W2_l, b2_l, h2, h, Nn, HIDC, 4 * HIDC);
    }

    // ---- output projection: out = h @ Wo^T + bo ----
    gemm_k<0, false><<<dim3(OUT_C / BN, mblk), blk, 0, stream>>>(h, Wo, bo, nullptr, outp, Nn, OUT_C, HIDC);
}

// Round 5
// 1304.961 us; speedup vs baseline: 1.6041x; 1.6041x over previous
//
#include <hip/hip_runtime.h>
#include <cmath>

#define HIDC   128
#define LAYERS 4
#define IN_C   64
#define OUT_C  64

typedef _Float16 h16x8 __attribute__((ext_vector_type(8)));
typedef float    f32x4 __attribute__((ext_vector_type(4)));

__device__ __forceinline__ float gelu_f(float x) {
    return 0.5f * x * (1.0f + erff(x * 0.70710678118654752f));
}

// ------------------------------ CSR build ------------------------------
__global__ void count_deg_k(const int* __restrict__ dst, int* __restrict__ cnt, int E) {
    int i = blockIdx.x * blockDim.x + threadIdx.x;
    if (i < E) atomicAdd(&cnt[dst[i]], 1);
}

__global__ __launch_bounds__(1024)
void scan_k(const int* __restrict__ cnt, int* __restrict__ rowptr, int n) {
    __shared__ int partials[1024];
    int tid = threadIdx.x;
    int per = (n + 1023) / 1024;
    int start = tid * per;
    int end = start + per; if (end > n) end = n;
    int s = 0;
    for (int i = start; i < end; ++i) s += cnt[i];
    partials[tid] = s;
    __syncthreads();
    for (int off = 1; off < 1024; off <<= 1) {
        int v = (tid >= off) ? partials[tid - off] : 0;
        __syncthreads();
        partials[tid] += v;
        __syncthreads();
    }
    int run = (tid == 0) ? 0 : partials[tid - 1];
    for (int i = start; i < end; ++i) { rowptr[i] = run; run += cnt[i]; }
    if (tid == 1023) rowptr[n] = partials[1023];
}

__global__ void scatter_k(const int* __restrict__ src, const int* __restrict__ dst,
                          const int* __restrict__ rowptr, int* __restrict__ cnt,
                          int* __restrict__ csrc, int E) {
    int i = blockIdx.x * blockDim.x + threadIdx.x;
    if (i < E) {
        int d = dst[i];
        int pos = rowptr[d] + atomicAdd(&cnt[d], 1);
        csrc[pos] = src[i];
    }
}

// --------------- MFMA fp16 GEMM: C = A @ W^T + bias (+gelu)(+resid) -------
// A: [M,K] fp32 row-major (converted to fp16 in-flight). W: [NC,K] fp32.
// Tile 128x128xBK32, 4 waves (2x2), wave tile 64x64 = 4x4 frags of 16x16x32.
// LDS stride 40 halfwords (+8 pad) -> 2-way bank alias on ds_read_b128 (free).
template<int ACT, bool RES, bool NGUARD>
__device__ __forceinline__ void gemm_core(
    const float* __restrict__ A, const float* __restrict__ Wt,
    const float* __restrict__ bias, const float* __restrict__ resid,
    float* __restrict__ Ct, int M, int K, int ncs, int colbase, int nclim)
{
    __shared__ __align__(16) _Float16 As[128 * 40];
    __shared__ __align__(16) _Float16 Bs[128 * 40];
    const int tid  = threadIdx.x;
    const int lane = tid & 63;
    const int wave = tid >> 6;
    const int wr = wave >> 1, wc = wave & 1;
    const int row0 = blockIdx.y * 128;

    f32x4 acc[4][4] = {};

    const int srow = tid >> 1;          // 0..127: tile row (A) / tile col (W)
    const int skc  = (tid & 1) * 16;    // k-offset within 32-wide K slice
    const int fr   = lane & 15;
    const int fk   = (lane >> 4) * 8;

    for (int k0 = 0; k0 < K; k0 += 32) {
        { // stage A tile (fp32 -> fp16)
            int gr = row0 + srow;
            float4 v0{}, v1{}, v2{}, v3{};
            if (gr < M) {
                const float* p = A + (size_t)gr * K + (k0 + skc);
                v0 = *(const float4*)(p);
                v1 = *(const float4*)(p + 4);
                v2 = *(const float4*)(p + 8);
                v3 = *(const float4*)(p + 12);
            }
            h16x8 h0, h1;
            h0[0]=(_Float16)v0.x; h0[1]=(_Float16)v0.y; h0[2]=(_Float16)v0.z; h0[3]=(_Float16)v0.w;
            h0[4]=(_Float16)v1.x; h0[5]=(_Float16)v1.y; h0[6]=(_Float16)v1.z; h0[7]=(_Float16)v1.w;
            h1[0]=(_Float16)v2.x; h1[1]=(_Float16)v2.y; h1[2]=(_Float16)v2.z; h1[3]=(_Float16)v2.w;
            h1[4]=(_Float16)v3.x; h1[5]=(_Float16)v3.y; h1[6]=(_Float16)v3.z; h1[7]=(_Float16)v3.w;
            *(h16x8*)(As + srow * 40 + skc)     = h0;
            *(h16x8*)(As + srow * 40 + skc + 8) = h1;
        }
        { // stage W tile (fp32 -> fp16); rows of W are output cols
            int gc = colbase + srow;
            float4 v0{}, v1{}, v2{}, v3{};
            if (!NGUARD || gc < nclim) {
                const float* p = Wt + (size_t)gc * K + (k0 + skc);
                v0 = *(const float4*)(p);
                v1 = *(const float4*)(p + 4);
                v2 = *(const float4*)(p + 8);
                v3 = *(const float4*)(p + 12);
            }
            h16x8 h0, h1;
            h0[0]=(_Float16)v0.x; h0[1]=(_Float16)v0.y; h0[2]=(_Float16)v0.z; h0[3]=(_Float16)v0.w;
            h0[4]=(_Float16)v1.x; h0[5]=(_Float16)v1.y; h0[6]=(_Float16)v1.z; h0[7]=(_Float16)v1.w;
            h1[0]=(_Float16)v2.x; h1[1]=(_Float16)v2.y; h1[2]=(_Float16)v2.z; h1[3]=(_Float16)v2.w;
            h1[4]=(_Float16)v3.x; h1[5]=(_Float16)v3.y; h1[6]=(_Float16)v3.z; h1[7]=(_Float16)v3.w;
            *(h16x8*)(Bs + srow * 40 + skc)     = h0;
            *(h16x8*)(Bs + srow * 40 + skc + 8) = h1;
        }
        __syncthreads();
        // fragments: a lane holds A[row=fr(+16mi)][k=fk..fk+7], W[col=fr(+16ni)][k=...]
        h16x8 af[4], bf[4];
#pragma unroll
        for (int mi = 0; mi < 4; ++mi)
            af[mi] = *(const h16x8*)(As + (wr * 64 + mi * 16 + fr) * 40 + fk);
#pragma unroll
        for (int ni = 0; ni < 4; ++ni)
            bf[ni] = *(const h16x8*)(Bs + (wc * 64 + ni * 16 + fr) * 40 + fk);
#pragma unroll
        for (int mi = 0; mi < 4; ++mi)
#pragma unroll
            for (int ni = 0; ni < 4; ++ni)
                acc[mi][ni] = __builtin_amdgcn_mfma_f32_16x16x32_f16(af[mi], bf[ni], acc[mi][ni], 0, 0, 0);
        __syncthreads();
    }

    // epilogue: C row = (lane>>4)*4 + j (+16mi +64wr), col = fr (+16ni +64wc)
    const int rbase = row0 + wr * 64 + ((lane >> 4) * 4);
    const int cbase = colbase + wc * 64 + fr;
#pragma unroll
    for (int mi = 0; mi < 4; ++mi) {
#pragma unroll
        for (int j = 0; j < 4; ++j) {
            int r = rbase + mi * 16 + j;
            if (r >= M) continue;
            size_t rb = (size_t)r * ncs;
#pragma unroll
            for (int ni = 0; ni < 4; ++ni) {
                int c = cbase + ni * 16;
                if (NGUARD && c >= nclim) continue;
                float v = acc[mi][ni][j] + bias[c];
                if (ACT == 1) v = gelu_f(v);
                if (RES) v += resid[rb + c];
                Ct[rb + c] = v;
            }
        }
    }
}

template<int ACT, bool RES, bool NGUARD>
__global__ __launch_bounds__(256)
void gemm_f16_k(const float* __restrict__ A, const float* __restrict__ W,
                const float* __restrict__ bias, const float* __restrict__ resid,
                float* __restrict__ C, int M, int NC, int K) {
    gemm_core<ACT, RES, NGUARD>(A, W, bias, resid, C, M, K, NC, blockIdx.x * 128, NC);
}

// fused Q/K/V/S: blockIdx.x picks projection; four separate [N,128] outputs
__global__ __launch_bounds__(256)
void gemm_qkvs_k(const float* __restrict__ A,
                 const float* __restrict__ W0, const float* __restrict__ W1,
                 const float* __restrict__ W2, const float* __restrict__ W3,
                 const float* __restrict__ B0, const float* __restrict__ B1,
                 const float* __restrict__ B2, const float* __restrict__ B3,
                 float* __restrict__ C0, float* __restrict__ C1,
                 float* __restrict__ C2, float* __restrict__ C3, int M, int K) {
    int b = blockIdx.x;
    const float* Wt = (b == 0) ? W0 : (b == 1) ? W1 : (b == 2) ? W2 : W3;
    const float* bt = (b == 0) ? B0 : (b == 1) ? B1 : (b == 2) ? B2 : B3;
    float*       Ct = (b == 0) ? C0 : (b == 1) ? C1 : (b == 2) ? C2 : C3;
    gemm_core<0, false, false>(A, Wt, bt, nullptr, Ct, M, K, 128, 0, 128);
}

// ------------------------------ Attention: one wave per dst node -----------
__global__ __launch_bounds__(256)
void attn_k(const float* __restrict__ Q, const float* __restrict__ K,
            const float* __restrict__ V, const int* __restrict__ rowptr,
            const int* __restrict__ csrc, float* __restrict__ out, int n) {
    int wave = (int)((blockIdx.x * (size_t)blockDim.x + threadIdx.x) >> 6);
    int lane = threadIdx.x & 63;
    if (wave >= n) return;
    size_t base = (size_t)wave * HIDC + lane * 2;
    float2 q = *(const float2*)(Q + base);
    float m = -INFINITY, ssum = 0.f;
    float accx = 0.f, accy = 0.f;
    int e0 = rowptr[wave], e1 = rowptr[wave + 1];
    for (int e = e0; e < e1; ++e) {
        int s = csrc[e];
        size_t sb = (size_t)s * HIDC + lane * 2;
        float2 k2 = *(const float2*)(K + sb);
        float2 v2 = *(const float2*)(V + sb);
        float d = q.x * k2.x + q.y * k2.y;
        d += __shfl_xor(d, 1);
        d += __shfl_xor(d, 2);
        d += __shfl_xor(d, 4);          // sum over the 8 lanes of this head
        float alpha = d * 0.25f;        // 1/sqrt(16)
        float mnew = fmaxf(m, alpha);
        float corr = expf(m - mnew);    // exp(-inf)=0 on first edge
        float w = expf(alpha - mnew);
        ssum = ssum * corr + w;
        accx = accx * corr + w * v2.x;
        accy = accy * corr + w * v2.y;
        m = mnew;
    }
    float inv = 1.f / (ssum + 1e-16f);
    float2 o = make_float2(accx * inv, accy * inv);
    *(float2*)(out + base) = o;
}

// --------------- beta gate + residual + layernorm: one wave per node -------
__global__ __launch_bounds__(256)
void beta_ln_k(const float* __restrict__ attn, const float* __restrict__ xr,
               const float* __restrict__ res, const float* __restrict__ Wb,
               const float* __restrict__ g, const float* __restrict__ b,
               float* __restrict__ out, int n) {
    int wave = (int)((blockIdx.x * (size_t)blockDim.x + threadIdx.x) >> 6);
    int lane = threadIdx.x & 63;
    if (wave >= n) return;
    size_t base = (size_t)wave * HIDC + lane * 2;
    int c = lane * 2;
    float2 o = *(const float2*)(attn + base);
    float2 r = *(const float2*)(xr + base);
    float2 wb0 = *(const float2*)(Wb + c);
    float2 wb1 = *(const float2*)(Wb + HIDC + c);
    float2 wb2 = *(const float2*)(Wb + 2 * HIDC + c);
    float part = o.x * wb0.x + o.y * wb0.y
               + r.x * wb1.x + r.y * wb1.y
               + (o.x - r.x) * wb2.x + (o.y - r.y) * wb2.y;
#pragma unroll
    for (int mk = 1; mk < 64; mk <<= 1) part += __shfl_xor(part, mk);
    float beta = 1.f / (1.f + expf(-part));
    float2 rs = *(const float2*)(res + base);
    float tx = beta * r.x + (1.f - beta) * o.x + rs.x;
    float ty = beta * r.y + (1.f - beta) * o.y + rs.y;
    float sum = tx + ty;
#pragma unroll
    for (int mk = 1; mk < 64; mk <<= 1) sum += __shfl_xor(sum, mk);
    float mean = sum * (1.f / 128.f);
    float dx = tx - mean, dy = ty - mean;
    float vs = dx * dx + dy * dy;
#pragma unroll
    for (int mk = 1; mk < 64; mk <<= 1) vs += __shfl_xor(vs, mk);
    float rstd = 1.f / sqrtf(vs * (1.f / 128.f) + 1e-5f);
    float2 gg = *(const float2*)(g + c);
    float2 bb = *(const float2*)(b + c);
    float2 oo = make_float2(dx * rstd * gg.x + bb.x, dy * rstd * gg.y + bb.y);
    *(float2*)(out + base) = oo;
}

// ------------------------------ host launch ------------------------------
extern "C" void kernel_launch(void* const* d_in, const int* in_sizes, int n_in,
                              void* d_out, int out_size, void* d_ws, size_t ws_size,
                              hipStream_t stream) {
    const float* x    = (const float*)d_in[0];
    const int*   ei   = (const int*)d_in[1];
    const float* Wi   = (const float*)d_in[2];
    const float* bi   = (const float*)d_in[3];
    const float* Wq   = (const float*)d_in[4];
    const float* bq   = (const float*)d_in[5];
    const float* Wk   = (const float*)d_in[6];
    const float* bk   = (const float*)d_in[7];
    const float* Wv   = (const float*)d_in[8];
    const float* bv   = (const float*)d_in[9];
    const float* Ws_  = (const float*)d_in[10];
    const float* bs   = (const float*)d_in[11];
    const float* Wbeta= (const float*)d_in[12];
    const float* ln_g = (const float*)d_in[13];
    const float* ln_b = (const float*)d_in[14];
    const float* W1   = (const float*)d_in[15];
    const float* b1   = (const float*)d_in[16];
    const float* W2   = (const float*)d_in[17];
    const float* b2   = (const float*)d_in[18];
    const float* Wo   = (const float*)d_in[19];
    const float* bo   = (const float*)d_in[20];
    float* outp = (float*)d_out;

    const int Nn = in_sizes[0] / IN_C;   // 50000
    const int Ee = in_sizes[1] / 2;      // 600000
    const int* srcI = ei;
    const int* dstI = ei + Ee;

    float* ws = (float*)d_ws;
    size_t n128 = (size_t)Nn * HIDC;
    float* h    = ws;                 // [N,128]
    float* h2   = h   + n128;         // [N,128]; also attention out
    float* qb   = h2  + n128;
    float* kb   = qb  + n128;
    float* vb   = kb  + n128;
    float* sb   = vb  + n128;
    float* ab   = h2;                 // alias
    float* ffn  = qb;                 // [N,512] aliases q/k/v/s
    int* rowptr = (int*)(sb + n128);
    int* cnt    = rowptr + (Nn + 1);
    int* csrc   = cnt + Nn;

    hipMemsetAsync(cnt, 0, Nn * sizeof(int), stream);
    count_deg_k<<<(Ee + 255) / 256, 256, 0, stream>>>(dstI, cnt, Ee);
    scan_k<<<1, 1024, 0, stream>>>(cnt, rowptr, Nn);
    hipMemsetAsync(cnt, 0, Nn * sizeof(int), stream);
    scatter_k<<<(Ee + 255) / 256, 256, 0, stream>>>(srcI, dstI, rowptr, cnt, csrc, Ee);

    const int mblk = (Nn + 127) / 128;   // 391
    dim3 blk(256);

    // input projection: h = gelu(x @ Wi^T + bi), K=64
    gemm_f16_k<1, false, false><<<dim3(1, mblk), blk, 0, stream>>>(x, Wi, bi, nullptr, h, Nn, HIDC, IN_C);

    int nwaveblk = (Nn + 3) / 4;

    for (int l = 0; l < LAYERS; ++l) {
        const float* Wq_l = Wq + (size_t)l * HIDC * HIDC;
        const float* Wk_l = Wk + (size_t)l * HIDC * HIDC;
        const float* Wv_l = Wv + (size_t)l * HIDC * HIDC;
        const float* Ws_l = Ws_ + (size_t)l * HIDC * HIDC;
        const float* bq_l = bq + (size_t)l * HIDC;
        const float* bk_l = bk + (size_t)l * HIDC;
        const float* bv_l = bv + (size_t)l * HIDC;
        const float* bs_l = bs + (size_t)l * HIDC;
        const float* Wb_l = Wbeta + (size_t)l * 3 * HIDC;
        const float* g_l  = ln_g + (size_t)l * HIDC;
        const float* b_l  = ln_b + (size_t)l * HIDC;
        const float* W1_l = W1 + (size_t)l * 4 * HIDC * HIDC;
        const float* b1_l = b1 + (size_t)l * 4 * HIDC;
        const float* W2_l = W2 + (size_t)l * HIDC * 4 * HIDC;
        const float* b2_l = b2 + (size_t)l * HIDC;

        // fused Q/K/V/S projections (one dispatch, 4x391 blocks)
        gemm_qkvs_k<<<dim3(4, mblk), blk, 0, stream>>>(h, Wq_l, Wk_l, Wv_l, Ws_l,
                                                       bq_l, bk_l, bv_l, bs_l,
                                                       qb, kb, vb, sb, Nn, HIDC);

        attn_k<<<nwaveblk, blk, 0, stream>>>(qb, kb, vb, rowptr, csrc, ab, Nn);

        beta_ln_k<<<nwaveblk, blk, 0, stream>>>(ab, sb, h, Wb_l, g_l, b_l, h2, Nn);

        // FFN1: ffn = gelu(h2 @ W1^T + b1)   [N,512]
        gemm_f16_k<1, false, false><<<dim3(4, mblk), blk, 0, stream>>>(h2, W1_l, b1_l, nullptr, ffn, Nn, 4 * HIDC, HIDC);
        // FFN2: h = ffn @ W2^T + b2 + h2     [N,128]
        gemm_f16_k<0, true, false><<<dim3(1, mblk), blk, 0, stream>>>(ffn, W2_l, b2_l, h2, h, Nn, HIDC, 4 * HIDC);
    }

    // output projection: out = h @ Wo^T + bo  (NC=64 -> guarded)
    gemm_f16_k<0, false, true><<<dim3(1, mblk), blk, 0, stream>>>(h, Wo, bo, nullptr, outp, Nn, OUT_C, HIDC);
}

// Round 6
// 1164.667 us; speedup vs baseline: 1.7973x; 1.1205x over previous
//
#include <hip/hip_runtime.h>
#include <cmath>

#define HIDC   128
#define LAYERS 4
#define IN_C   64
#define OUT_C  64

typedef _Float16 h16x8 __attribute__((ext_vector_type(8)));
typedef _Float16 h16x2 __attribute__((ext_vector_type(2)));
typedef float    f32x4 __attribute__((ext_vector_type(4)));

__device__ __forceinline__ float gelu_f(float x) {
    return 0.5f * x * (1.0f + erff(x * 0.70710678118654752f));
}

__device__ __forceinline__ void cvt8(const float4& a, const float4& b, h16x8& h) {
    h[0]=(_Float16)a.x; h[1]=(_Float16)a.y; h[2]=(_Float16)a.z; h[3]=(_Float16)a.w;
    h[4]=(_Float16)b.x; h[5]=(_Float16)b.y; h[6]=(_Float16)b.z; h[7]=(_Float16)b.w;
}
// stage 16 contiguous elements from global into LDS as fp16
__device__ __forceinline__ void load16(const float* p, _Float16* d) {
    float4 v0 = *(const float4*)p,     v1 = *(const float4*)(p + 4);
    float4 v2 = *(const float4*)(p+8), v3 = *(const float4*)(p + 12);
    h16x8 h0, h1; cvt8(v0, v1, h0); cvt8(v2, v3, h1);
    *(h16x8*)d = h0; *(h16x8*)(d + 8) = h1;
}
__device__ __forceinline__ void load16(const _Float16* p, _Float16* d) {
    *(h16x8*)d = *(const h16x8*)p; *(h16x8*)(d + 8) = *(const h16x8*)(p + 8);
}
__device__ __forceinline__ void zero16(_Float16* d) {
    h16x8 z = {};
    *(h16x8*)d = z; *(h16x8*)(d + 8) = z;
}

// ------------------------------ CSR build ------------------------------
__global__ void count_deg_k(const int* __restrict__ dst, int* __restrict__ cnt, int E) {
    int i = blockIdx.x * blockDim.x + threadIdx.x;
    if (i < E) atomicAdd(&cnt[dst[i]], 1);
}

__global__ __launch_bounds__(1024)
void scan_k(const int* __restrict__ cnt, int* __restrict__ rowptr, int n) {
    __shared__ int partials[1024];
    int tid = threadIdx.x;
    int per = (n + 1023) / 1024;
    int start = tid * per;
    int end = start + per; if (end > n) end = n;
    int s = 0;
    for (int i = start; i < end; ++i) s += cnt[i];
    partials[tid] = s;
    __syncthreads();
    for (int off = 1; off < 1024; off <<= 1) {
        int v = (tid >= off) ? partials[tid - off] : 0;
        __syncthreads();
        partials[tid] += v;
        __syncthreads();
    }
    int run = (tid == 0) ? 0 : partials[tid - 1];
    for (int i = start; i < end; ++i) { rowptr[i] = run; run += cnt[i]; }
    if (tid == 1023) rowptr[n] = partials[1023];
}

__global__ void scatter_k(const int* __restrict__ src, const int* __restrict__ dst,
                          const int* __restrict__ rowptr, int* __restrict__ cnt,
                          int* __restrict__ csrc, int E) {
    int i = blockIdx.x * blockDim.x + threadIdx.x;
    if (i < E) {
        int d = dst[i];
        int pos = rowptr[d] + atomicAdd(&cnt[d], 1);
        csrc[pos] = src[i];
    }
}

// --------------- generic MFMA fp16 GEMM: C = A @ W^T + bias (+gelu)(+res) --
// Tile 128x128xBK32, 4 waves 2x2, wave 64x64 = 4x4 frags of 16x16x32.
template<int ACT, bool RES, bool NGUARD, typename AT, typename CT>
__device__ __forceinline__ void gemm_core(
    const AT* __restrict__ A, const float* __restrict__ Wt,
    const float* __restrict__ bias, const float* __restrict__ resid,
    CT* __restrict__ Ct, int M, int K, int ncs, int colbase, int nclim)
{
    __shared__ __align__(16) _Float16 As[128 * 40];
    __shared__ __align__(16) _Float16 Bs[128 * 40];
    const int tid  = threadIdx.x;
    const int lane = tid & 63;
    const int wave = tid >> 6;
    const int wr = wave >> 1, wc = wave & 1;
    const int row0 = blockIdx.y * 128;

    f32x4 acc[4][4] = {};

    const int srow = tid >> 1;          // 0..127
    const int skc  = (tid & 1) * 16;    // k offset in 32-wide slice
    const int fr   = lane & 15;
    const int fk   = (lane >> 4) * 8;

    for (int k0 = 0; k0 < K; k0 += 32) {
        {
            int gr = row0 + srow;
            _Float16* d = As + srow * 40 + skc;
            if (gr < M) load16(A + (size_t)gr * K + k0 + skc, d);
            else        zero16(d);
        }
        {
            int gc = colbase + srow;
            _Float16* d = Bs + srow * 40 + skc;
            if (!NGUARD || gc < nclim) load16(Wt + (size_t)gc * K + k0 + skc, d);
            else                       zero16(d);
        }
        __syncthreads();
        h16x8 af[4], bf[4];
#pragma unroll
        for (int mi = 0; mi < 4; ++mi)
            af[mi] = *(const h16x8*)(As + (wr * 64 + mi * 16 + fr) * 40 + fk);
#pragma unroll
        for (int ni = 0; ni < 4; ++ni)
            bf[ni] = *(const h16x8*)(Bs + (wc * 64 + ni * 16 + fr) * 40 + fk);
#pragma unroll
        for (int mi = 0; mi < 4; ++mi)
#pragma unroll
            for (int ni = 0; ni < 4; ++ni)
                acc[mi][ni] = __builtin_amdgcn_mfma_f32_16x16x32_f16(af[mi], bf[ni], acc[mi][ni], 0, 0, 0);
        __syncthreads();
    }

    const int rbase = row0 + wr * 64 + ((lane >> 4) * 4);
    const int cbase = colbase + wc * 64 + fr;
#pragma unroll
    for (int mi = 0; mi < 4; ++mi) {
#pragma unroll
        for (int j = 0; j < 4; ++j) {
            int r = rbase + mi * 16 + j;
            if (r >= M) continue;
            size_t rb = (size_t)r * ncs;
#pragma unroll
            for (int ni = 0; ni < 4; ++ni) {
                int c = cbase + ni * 16;
                if (NGUARD && c >= nclim) continue;
                float v = acc[mi][ni][j] + bias[c];
                if (ACT == 1) v = gelu_f(v);
                if (RES) v += resid[rb + c];
                Ct[rb + c] = (CT)v;
            }
        }
    }
}

template<int ACT, bool RES, bool NGUARD, typename AT, typename CT>
__global__ __launch_bounds__(256)
void gemm_f16_k(const AT* __restrict__ A, const float* __restrict__ W,
                const float* __restrict__ bias, const float* __restrict__ resid,
                CT* __restrict__ C, int M, int NC, int K) {
    gemm_core<ACT, RES, NGUARD, AT, CT>(A, W, bias, resid, C, M, K, NC, blockIdx.x * 128, NC);
}

// --------- fused Q/K/V/S: stage A once, loop 4 weight sets ------------------
// outputs: q fp32 [N,128]; kv fp16 [N,256] (k | v interleaved); s fp32 [N,128]
__global__ __launch_bounds__(256)
void qkvs_k(const float* __restrict__ A,
            const float* __restrict__ Wq, const float* __restrict__ Wk,
            const float* __restrict__ Wv, const float* __restrict__ Wvs,
            const float* __restrict__ bq, const float* __restrict__ bk,
            const float* __restrict__ bv, const float* __restrict__ bs,
            float* __restrict__ qb, _Float16* __restrict__ kv,
            float* __restrict__ sb, int M) {
    __shared__ __align__(16) _Float16 As[128 * 136];
    __shared__ __align__(16) _Float16 Bs[128 * 136];
    const int tid  = threadIdx.x;
    const int lane = tid & 63;
    const int wave = tid >> 6;
    const int wr = wave >> 1, wc = wave & 1;
    const int row0 = blockIdx.x * 128;
    const int srow  = tid >> 1;
    const int shalf = (tid & 1) * 64;
    const int fr = lane & 15;

    { // stage full A tile 128x128 fp32->fp16 (read h ONCE per row-slab)
        int gr = row0 + srow;
        _Float16* d = As + srow * 136 + shalf;
        if (gr < M) {
            const float* p = A + (size_t)gr * 128 + shalf;
#pragma unroll
            for (int u = 0; u < 4; ++u) load16(p + u * 16, d + u * 16);
        } else {
#pragma unroll
            for (int u = 0; u < 4; ++u) zero16(d + u * 16);
        }
    }

    for (int w = 0; w < 4; ++w) {
        const float* Wp = (w == 0) ? Wq : (w == 1) ? Wk : (w == 2) ? Wv : Wvs;
        const float* bp = (w == 0) ? bq : (w == 1) ? bk : (w == 2) ? bv : bs;
        { // stage full W tile (L2-resident broadcast)
            const float* p = Wp + (size_t)srow * 128 + shalf;
            _Float16* d = Bs + srow * 136 + shalf;
#pragma unroll
            for (int u = 0; u < 4; ++u) load16(p + u * 16, d + u * 16);
        }
        __syncthreads();
        f32x4 acc[4][4] = {};
#pragma unroll
        for (int ks = 0; ks < 4; ++ks) {
            const int fk = ks * 32 + (lane >> 4) * 8;
            h16x8 af[4], bf[4];
#pragma unroll
            for (int mi = 0; mi < 4; ++mi)
                af[mi] = *(const h16x8*)(As + (wr * 64 + mi * 16 + fr) * 136 + fk);
#pragma unroll
            for (int ni = 0; ni < 4; ++ni)
                bf[ni] = *(const h16x8*)(Bs + (wc * 64 + ni * 16 + fr) * 136 + fk);
#pragma unroll
            for (int mi = 0; mi < 4; ++mi)
#pragma unroll
                for (int ni = 0; ni < 4; ++ni)
                    acc[mi][ni] = __builtin_amdgcn_mfma_f32_16x16x32_f16(af[mi], bf[ni], acc[mi][ni], 0, 0, 0);
        }
        __syncthreads();   // Bs reads done before next w restages

        const int rbase = row0 + wr * 64 + ((lane >> 4) * 4);
        const int cbase = wc * 64 + fr;
#pragma unroll
        for (int mi = 0; mi < 4; ++mi) {
#pragma unroll
            for (int j = 0; j < 4; ++j) {
                int r = rbase + mi * 16 + j;
                if (r >= M) continue;
#pragma unroll
                for (int ni = 0; ni < 4; ++ni) {
                    int c = cbase + ni * 16;
                    float v = acc[mi][ni][j] + bp[c];
                    if (w == 0)      qb[(size_t)r * 128 + c] = v;
                    else if (w == 1) kv[(size_t)r * 256 + c] = (_Float16)v;
                    else if (w == 2) kv[(size_t)r * 256 + 128 + c] = (_Float16)v;
                    else             sb[(size_t)r * 128 + c] = v;
                }
            }
        }
    }
}

// ---- fused attention + beta gate + residual + LN: one wave per dst node ----
__global__ __launch_bounds__(256)
void attn_ln_k(const float* __restrict__ Q, const _Float16* __restrict__ kv,
               const int* __restrict__ rowptr, const int* __restrict__ csrc,
               const float* __restrict__ xr, const float* __restrict__ res,
               const float* __restrict__ Wb, const float* __restrict__ g,
               const float* __restrict__ b, float* __restrict__ out, int n) {
    int node = (int)((blockIdx.x * (size_t)blockDim.x + threadIdx.x) >> 6);
    int lane = threadIdx.x & 63;
    if (node >= n) return;
    size_t base = (size_t)node * HIDC + lane * 2;
    float2 q = *(const float2*)(Q + base);
    float m = -INFINITY, ssum = 0.f, accx = 0.f, accy = 0.f;
    int e0 = rowptr[node], e1 = rowptr[node + 1];
    for (int e = e0; e < e1; ++e) {
        int s = csrc[e];
        const _Float16* kp = kv + (size_t)s * 256 + lane * 2;
        h16x2 k2 = *(const h16x2*)(kp);
        h16x2 v2 = *(const h16x2*)(kp + 128);
        float d = q.x * (float)k2[0] + q.y * (float)k2[1];
        d += __shfl_xor(d, 1);
        d += __shfl_xor(d, 2);
        d += __shfl_xor(d, 4);          // 8-lane (one head) reduce
        float alpha = d * 0.25f;        // 1/sqrt(16)
        float mnew = fmaxf(m, alpha);
        float corr = expf(m - mnew);
        float w = expf(alpha - mnew);
        ssum = ssum * corr + w;
        accx = accx * corr + w * (float)v2[0];
        accy = accy * corr + w * (float)v2[1];
        m = mnew;
    }
    float inv = 1.f / (ssum + 1e-16f);
    float ox = accx * inv, oy = accy * inv;

    // ---- beta gate + residual + LN ----
    int c = lane * 2;
    float2 r  = *(const float2*)(xr + base);
    float2 wb0 = *(const float2*)(Wb + c);
    float2 wb1 = *(const float2*)(Wb + HIDC + c);
    float2 wb2 = *(const float2*)(Wb + 2 * HIDC + c);
    float part = ox * wb0.x + oy * wb0.y
               + r.x * wb1.x + r.y * wb1.y
               + (ox - r.x) * wb2.x + (oy - r.y) * wb2.y;
#pragma unroll
    for (int mk = 1; mk < 64; mk <<= 1) part += __shfl_xor(part, mk);
    float beta = 1.f / (1.f + expf(-part));
    float2 rs = *(const float2*)(res + base);
    float tx = beta * r.x + (1.f - beta) * ox + rs.x;
    float ty = beta * r.y + (1.f - beta) * oy + rs.y;
    float sum = tx + ty;
#pragma unroll
    for (int mk = 1; mk < 64; mk <<= 1) sum += __shfl_xor(sum, mk);
    float mean = sum * (1.f / 128.f);
    float dx = tx - mean, dy = ty - mean;
    float vs = dx * dx + dy * dy;
#pragma unroll
    for (int mk = 1; mk < 64; mk <<= 1) vs += __shfl_xor(vs, mk);
    float rstd = 1.f / sqrtf(vs * (1.f / 128.f) + 1e-5f);
    float2 gg = *(const float2*)(g + c);
    float2 bb = *(const float2*)(b + c);
    float2 oo = make_float2(dx * rstd * gg.x + bb.x, dy * rstd * gg.y + bb.y);
    *(float2*)(out + base) = oo;
}

// ------------------------------ host launch ------------------------------
extern "C" void kernel_launch(void* const* d_in, const int* in_sizes, int n_in,
                              void* d_out, int out_size, void* d_ws, size_t ws_size,
                              hipStream_t stream) {
    const float* x    = (const float*)d_in[0];
    const int*   ei   = (const int*)d_in[1];
    const float* Wi   = (const float*)d_in[2];
    const float* bi   = (const float*)d_in[3];
    const float* Wq   = (const float*)d_in[4];
    const float* bq   = (const float*)d_in[5];
    const float* Wk   = (const float*)d_in[6];
    const float* bk   = (const float*)d_in[7];
    const float* Wv   = (const float*)d_in[8];
    const float* bv   = (const float*)d_in[9];
    const float* Ws_  = (const float*)d_in[10];
    const float* bs   = (const float*)d_in[11];
    const float* Wbeta= (const float*)d_in[12];
    const float* ln_g = (const float*)d_in[13];
    const float* ln_b = (const float*)d_in[14];
    const float* W1   = (const float*)d_in[15];
    const float* b1   = (const float*)d_in[16];
    const float* W2   = (const float*)d_in[17];
    const float* b2   = (const float*)d_in[18];
    const float* Wo   = (const float*)d_in[19];
    const float* bo   = (const float*)d_in[20];
    float* outp = (float*)d_out;

    const int Nn = in_sizes[0] / IN_C;   // 50000
    const int Ee = in_sizes[1] / 2;      // 600000
    const int* srcI = ei;
    const int* dstI = ei + Ee;

    // workspace: h | h2 | qb | kv(fp16,[N,256]) | sb | ints   (~128 MB + 2.6 MB)
    float* ws = (float*)d_ws;
    size_t n128 = (size_t)Nn * HIDC;
    float*     h   = ws;
    float*     h2  = h  + n128;
    float*     qb  = h2 + n128;
    _Float16*  kv  = (_Float16*)(qb + n128);     // N*256 fp16 = n128 floats
    float*     sb  = qb + 2 * n128;
    _Float16*  ffn = (_Float16*)qb;              // [N,512] fp16 aliases qb+kv
    int* rowptr = (int*)(sb + n128);
    int* cnt    = rowptr + (Nn + 1);
    int* csrc   = cnt + Nn;

    hipMemsetAsync(cnt, 0, Nn * sizeof(int), stream);
    count_deg_k<<<(Ee + 255) / 256, 256, 0, stream>>>(dstI, cnt, Ee);
    scan_k<<<1, 1024, 0, stream>>>(cnt, rowptr, Nn);
    hipMemsetAsync(cnt, 0, Nn * sizeof(int), stream);
    scatter_k<<<(Ee + 255) / 256, 256, 0, stream>>>(srcI, dstI, rowptr, cnt, csrc, Ee);

    const int mblk = (Nn + 127) / 128;   // 391
    dim3 blk(256);

    // input projection: h = gelu(x @ Wi^T + bi), K=64
    gemm_f16_k<1, false, false, float, float><<<dim3(1, mblk), blk, 0, stream>>>(x, Wi, bi, nullptr, h, Nn, HIDC, IN_C);

    int nwaveblk = (Nn + 3) / 4;

    for (int l = 0; l < LAYERS; ++l) {
        const float* Wq_l = Wq + (size_t)l * HIDC * HIDC;
        const float* Wk_l = Wk + (size_t)l * HIDC * HIDC;
        const float* Wv_l = Wv + (size_t)l * HIDC * HIDC;
        const float* Ws_l = Ws_ + (size_t)l * HIDC * HIDC;
        const float* bq_l = bq + (size_t)l * HIDC;
        const float* bk_l = bk + (size_t)l * HIDC;
        const float* bv_l = bv + (size_t)l * HIDC;
        const float* bs_l = bs + (size_t)l * HIDC;
        const float* Wb_l = Wbeta + (size_t)l * 3 * HIDC;
        const float* g_l  = ln_g + (size_t)l * HIDC;
        const float* b_l  = ln_b + (size_t)l * HIDC;
        const float* W1_l = W1 + (size_t)l * 4 * HIDC * HIDC;
        const float* b1_l = b1 + (size_t)l * 4 * HIDC;
        const float* W2_l = W2 + (size_t)l * HIDC * 4 * HIDC;
        const float* b2_l = b2 + (size_t)l * HIDC;

        qkvs_k<<<dim3(mblk), blk, 0, stream>>>(h, Wq_l, Wk_l, Wv_l, Ws_l,
                                               bq_l, bk_l, bv_l, bs_l,
                                               qb, kv, sb, Nn);

        attn_ln_k<<<nwaveblk, blk, 0, stream>>>(qb, kv, rowptr, csrc,
                                                sb, h, Wb_l, g_l, b_l, h2, Nn);

        // FFN1: ffn(fp16) = gelu(h2 @ W1^T + b1)   [N,512]
        gemm_f16_k<1, false, false, float, _Float16><<<dim3(4, mblk), blk, 0, stream>>>(h2, W1_l, b1_l, nullptr, ffn, Nn, 4 * HIDC, HIDC);
        // FFN2: h = ffn @ W2^T + b2 + h2           [N,128]
        gemm_f16_k<0, true, false, _Float16, float><<<dim3(1, mblk), blk, 0, stream>>>(ffn, W2_l, b2_l, h2, h, Nn, HIDC, 4 * HIDC);
    }

    // output projection: out = h @ Wo^T + bo  (NC=64, guarded)
    gemm_f16_k<0, false, true, float, float><<<dim3(1, mblk), blk, 0, stream>>>(h, Wo, bo, nullptr, outp, Nn, OUT_C, HIDC);
}

// Round 8
// 1038.306 us; speedup vs baseline: 2.0161x; 1.1217x over previous
//
#include <hip/hip_runtime.h>
#include <cmath>

#define HIDC   128
#define LAYERS 4
#define IN_C   64
#define OUT_C  64

typedef _Float16 h16x8 __attribute__((ext_vector_type(8)));
typedef _Float16 h16x2 __attribute__((ext_vector_type(2)));
typedef float    f32x4 __attribute__((ext_vector_type(4)));

__device__ __forceinline__ float gelu_f(float x) {
    return 0.5f * x * (1.0f + erff(x * 0.70710678118654752f));
}

__device__ __forceinline__ void cvt8(const float4& a, const float4& b, h16x8& h) {
    h[0]=(_Float16)a.x; h[1]=(_Float16)a.y; h[2]=(_Float16)a.z; h[3]=(_Float16)a.w;
    h[4]=(_Float16)b.x; h[5]=(_Float16)b.y; h[6]=(_Float16)b.z; h[7]=(_Float16)b.w;
}
__device__ __forceinline__ void load16(const float* p, _Float16* d) {
    float4 v0 = *(const float4*)p,     v1 = *(const float4*)(p + 4);
    float4 v2 = *(const float4*)(p+8), v3 = *(const float4*)(p + 12);
    h16x8 h0, h1; cvt8(v0, v1, h0); cvt8(v2, v3, h1);
    *(h16x8*)d = h0; *(h16x8*)(d + 8) = h1;
}
__device__ __forceinline__ void load16(const _Float16* p, _Float16* d) {
    *(h16x8*)d = *(const h16x8*)p; *(h16x8*)(d + 8) = *(const h16x8*)(p + 8);
}
__device__ __forceinline__ void zero16(_Float16* d) {
    h16x8 z = {};
    *(h16x8*)d = z; *(h16x8*)(d + 8) = z;
}

// ------------------------------ CSR build ------------------------------
__global__ void count_deg_k(const int* __restrict__ dst, int* __restrict__ cnt, int E) {
    int i = blockIdx.x * blockDim.x + threadIdx.x;
    if (i < E) atomicAdd(&cnt[dst[i]], 1);
}

__global__ __launch_bounds__(1024)
void scan_k(const int* __restrict__ cnt, int* __restrict__ rowptr, int n) {
    __shared__ int partials[1024];
    int tid = threadIdx.x;
    int per = (n + 1023) / 1024;
    int start = tid * per;
    int end = start + per; if (end > n) end = n;
    int s = 0;
    for (int i = start; i < end; ++i) s += cnt[i];
    partials[tid] = s;
    __syncthreads();
    for (int off = 1; off < 1024; off <<= 1) {
        int v = (tid >= off) ? partials[tid - off] : 0;
        __syncthreads();
        partials[tid] += v;
        __syncthreads();
    }
    int run = (tid == 0) ? 0 : partials[tid - 1];
    for (int i = start; i < end; ++i) { rowptr[i] = run; run += cnt[i]; }
    if (tid == 1023) rowptr[n] = partials[1023];
}

__global__ void scatter_k(const int* __restrict__ src, const int* __restrict__ dst,
                          const int* __restrict__ rowptr, int* __restrict__ cnt,
                          int* __restrict__ csrc, int E) {
    int i = blockIdx.x * blockDim.x + threadIdx.x;
    if (i < E) {
        int d = dst[i];
        int pos = rowptr[d] + atomicAdd(&cnt[d], 1);
        csrc[pos] = src[i];
    }
}

// --------------- generic MFMA fp16 GEMM: C = A @ W^T + bias (+gelu)(+res) --
template<int ACT, bool RES, bool NGUARD, typename AT, typename CT>
__device__ __forceinline__ void gemm_core(
    const AT* __restrict__ A, const float* __restrict__ Wt,
    const float* __restrict__ bias, const float* __restrict__ resid,
    CT* __restrict__ Ct, int M, int K, int ncs, int colbase, int nclim)
{
    __shared__ __align__(16) _Float16 As[128 * 40];
    __shared__ __align__(16) _Float16 Bs[128 * 40];
    const int tid  = threadIdx.x;
    const int lane = tid & 63;
    const int wave = tid >> 6;
    const int wr = wave >> 1, wc = wave & 1;
    const int row0 = blockIdx.y * 128;

    f32x4 acc[4][4] = {};

    const int srow = tid >> 1;
    const int skc  = (tid & 1) * 16;
    const int fr   = lane & 15;
    const int fk   = (lane >> 4) * 8;

    for (int k0 = 0; k0 < K; k0 += 32) {
        {
            int gr = row0 + srow;
            _Float16* d = As + srow * 40 + skc;
            if (gr < M) load16(A + (size_t)gr * K + k0 + skc, d);
            else        zero16(d);
        }
        {
            int gc = colbase + srow;
            _Float16* d = Bs + srow * 40 + skc;
            if (!NGUARD || gc < nclim) load16(Wt + (size_t)gc * K + k0 + skc, d);
            else                       zero16(d);
        }
        __syncthreads();
        h16x8 af[4], bf[4];
#pragma unroll
        for (int mi = 0; mi < 4; ++mi)
            af[mi] = *(const h16x8*)(As + (wr * 64 + mi * 16 + fr) * 40 + fk);
#pragma unroll
        for (int ni = 0; ni < 4; ++ni)
            bf[ni] = *(const h16x8*)(Bs + (wc * 64 + ni * 16 + fr) * 40 + fk);
#pragma unroll
        for (int mi = 0; mi < 4; ++mi)
#pragma unroll
            for (int ni = 0; ni < 4; ++ni)
                acc[mi][ni] = __builtin_amdgcn_mfma_f32_16x16x32_f16(af[mi], bf[ni], acc[mi][ni], 0, 0, 0);
        __syncthreads();
    }

    const int rbase = row0 + wr * 64 + ((lane >> 4) * 4);
    const int cbase = colbase + wc * 64 + fr;
#pragma unroll
    for (int mi = 0; mi < 4; ++mi) {
#pragma unroll
        for (int j = 0; j < 4; ++j) {
            int r = rbase + mi * 16 + j;
            if (r >= M) continue;
            size_t rb = (size_t)r * ncs;
#pragma unroll
            for (int ni = 0; ni < 4; ++ni) {
                int c = cbase + ni * 16;
                if (NGUARD && c >= nclim) continue;
                float v = acc[mi][ni][j] + bias[c];
                if (ACT == 1) v = gelu_f(v);
                if (RES) v += resid[rb + c];
                Ct[rb + c] = (CT)v;
            }
        }
    }
}

template<int ACT, bool RES, bool NGUARD, typename AT, typename CT>
__global__ __launch_bounds__(256)
void gemm_f16_k(const AT* __restrict__ A, const float* __restrict__ W,
                const float* __restrict__ bias, const float* __restrict__ resid,
                CT* __restrict__ C, int M, int NC, int K) {
    gemm_core<ACT, RES, NGUARD, AT, CT>(A, W, bias, resid, C, M, K, NC, blockIdx.x * 128, NC);
}

// --------- fused Q/K/V/S: stage A once, loop 4 weight sets ------------------
// outputs: qh fp16 [N,128]; kv fp16 [N,256] (k|v); sb fp32 [N,128]
__global__ __launch_bounds__(256)
void qkvs_k(const float* __restrict__ A,
            const float* __restrict__ Wq, const float* __restrict__ Wk,
            const float* __restrict__ Wv, const float* __restrict__ Wvs,
            const float* __restrict__ bq, const float* __restrict__ bk,
            const float* __restrict__ bv, const float* __restrict__ bs,
            _Float16* __restrict__ qh, _Float16* __restrict__ kv,
            float* __restrict__ sb, int M) {
    __shared__ __align__(16) _Float16 As[128 * 136];
    __shared__ __align__(16) _Float16 Bs[128 * 136];
    const int tid  = threadIdx.x;
    const int lane = tid & 63;
    const int wave = tid >> 6;
    const int wr = wave >> 1, wc = wave & 1;
    const int row0 = blockIdx.x * 128;
    const int srow  = tid >> 1;
    const int shalf = (tid & 1) * 64;
    const int fr = lane & 15;

    { // stage full A tile 128x128 fp32->fp16 (read h once per row-slab)
        int gr = row0 + srow;
        _Float16* d = As + srow * 136 + shalf;
        if (gr < M) {
            const float* p = A + (size_t)gr * 128 + shalf;
#pragma unroll
            for (int u = 0; u < 4; ++u) load16(p + u * 16, d + u * 16);
        } else {
#pragma unroll
            for (int u = 0; u < 4; ++u) zero16(d + u * 16);
        }
    }

    for (int w = 0; w < 4; ++w) {
        const float* Wp = (w == 0) ? Wq : (w == 1) ? Wk : (w == 2) ? Wv : Wvs;
        const float* bp = (w == 0) ? bq : (w == 1) ? bk : (w == 2) ? bv : bs;
        {
            const float* p = Wp + (size_t)srow * 128 + shalf;
            _Float16* d = Bs + srow * 136 + shalf;
#pragma unroll
            for (int u = 0; u < 4; ++u) load16(p + u * 16, d + u * 16);
        }
        __syncthreads();
        f32x4 acc[4][4] = {};
#pragma unroll
        for (int ks = 0; ks < 4; ++ks) {
            const int fk = ks * 32 + (lane >> 4) * 8;
            h16x8 af[4], bf[4];
#pragma unroll
            for (int mi = 0; mi < 4; ++mi)
                af[mi] = *(const h16x8*)(As + (wr * 64 + mi * 16 + fr) * 136 + fk);
#pragma unroll
            for (int ni = 0; ni < 4; ++ni)
                bf[ni] = *(const h16x8*)(Bs + (wc * 64 + ni * 16 + fr) * 136 + fk);
#pragma unroll
            for (int mi = 0; mi < 4; ++mi)
#pragma unroll
                for (int ni = 0; ni < 4; ++ni)
                    acc[mi][ni] = __builtin_amdgcn_mfma_f32_16x16x32_f16(af[mi], bf[ni], acc[mi][ni], 0, 0, 0);
        }
        __syncthreads();

        const int rbase = row0 + wr * 64 + ((lane >> 4) * 4);
        const int cbase = wc * 64 + fr;
#pragma unroll
        for (int mi = 0; mi < 4; ++mi) {
#pragma unroll
            for (int j = 0; j < 4; ++j) {
                int r = rbase + mi * 16 + j;
                if (r >= M) continue;
#pragma unroll
                for (int ni = 0; ni < 4; ++ni) {
                    int c = cbase + ni * 16;
                    float v = acc[mi][ni][j] + bp[c];
                    if (w == 0)      qh[(size_t)r * 128 + c] = (_Float16)v;
                    else if (w == 1) kv[(size_t)r * 256 + c] = (_Float16)v;
                    else if (w == 2) kv[(size_t)r * 256 + 128 + c] = (_Float16)v;
                    else             sb[(size_t)r * 128 + c] = v;
                }
            }
        }
    }
}

// ---- fused attention + beta gate + residual + LN -------------------------
// One wave per dst node. Lane = (g = lane&7 edge-slot, h = lane>>3 head).
// Each lane computes the full 16-dim dot for (edge g, head h): no per-edge
// shuffles, 8 edges in flight. No online max (|alpha| << 88, exp safe;
// max-subtraction cancels exactly in the softmax ratio).
__global__ __launch_bounds__(256)
void attn_ln_k(const _Float16* __restrict__ qh, const _Float16* __restrict__ kv,
               const int* __restrict__ rowptr, const int* __restrict__ csrc,
               const float* __restrict__ xr, const float* __restrict__ res,
               const float* __restrict__ Wb, const float* __restrict__ g_,
               const float* __restrict__ b_, float* __restrict__ out, int n) {
    int node = (int)((blockIdx.x * (size_t)blockDim.x + threadIdx.x) >> 6);
    int lane = threadIdx.x & 63;
    if (node >= n) return;
    const int g = lane & 7;     // edge slot in batch
    const int h = lane >> 3;    // head

    const _Float16* qp = qh + (size_t)node * 128 + h * 16;
    h16x8 q0 = *(const h16x8*)(qp);
    h16x8 q1 = *(const h16x8*)(qp + 8);

    float ssum = 0.f;
    float acc[16] = {};
    const int e0 = rowptr[node], e1 = rowptr[node + 1];
    for (int eb = e0; eb < e1; eb += 8) {
        int e = eb + g;
        bool val = (e < e1);
        int s = csrc[val ? e : (e1 - 1)];
        const _Float16* kp = kv + (size_t)s * 256 + h * 16;
        h16x8 k0 = *(const h16x8*)(kp);
        h16x8 k1 = *(const h16x8*)(kp + 8);
        h16x8 v0 = *(const h16x8*)(kp + 128);
        h16x8 v1 = *(const h16x8*)(kp + 136);
        float d = 0.f;
#pragma unroll
        for (int j = 0; j < 8; ++j) d += (float)k0[j] * (float)q0[j];
#pragma unroll
        for (int j = 0; j < 8; ++j) d += (float)k1[j] * (float)q1[j];
        float w = val ? __expf(d * 0.25f) : 0.f;
        ssum += w;
#pragma unroll
        for (int j = 0; j < 8; ++j) acc[j]     += w * (float)v0[j];
#pragma unroll
        for (int j = 0; j < 8; ++j) acc[8 + j] += w * (float)v1[j];
    }
    // reduce over the 8 edge-slots (octet butterfly; h invariant under xor<8)
#pragma unroll
    for (int m = 1; m < 8; m <<= 1) {
        ssum += __shfl_xor(ssum, m);
#pragma unroll
        for (int j = 0; j < 16; ++j) acc[j] += __shfl_xor(acc[j], m);
    }
    float inv = 1.f / (ssum + 1e-16f);
    // lane owns channels (2*lane, 2*lane+1) = head h, within-head 2g, 2g+1:
    // select acc[2g], acc[2g+1] via compile-time-indexed cndmask tree.
    const bool s0b = g & 1, s1b = g & 2, s2b = g & 4;
    float t0 = s0b ? acc[2]  : acc[0],  t1 = s0b ? acc[6]  : acc[4];
    float t2 = s0b ? acc[10] : acc[8],  t3 = s0b ? acc[14] : acc[12];
    float u0 = s1b ? t1 : t0,           u1 = s1b ? t3 : t2;
    float ox = (s2b ? u1 : u0) * inv;
    float p0 = s0b ? acc[3]  : acc[1],  p1 = s0b ? acc[7]  : acc[5];
    float p2 = s0b ? acc[11] : acc[9],  p3 = s0b ? acc[15] : acc[13];
    float w0 = s1b ? p1 : p0,           w1 = s1b ? p3 : p2;
    float oy = (s2b ? w1 : w0) * inv;

    // ---- beta gate + residual + LN ----
    size_t base = (size_t)node * HIDC + lane * 2;
    int c = lane * 2;
    float2 r  = *(const float2*)(xr + base);
    float2 wb0 = *(const float2*)(Wb + c);
    float2 wb1 = *(const float2*)(Wb + HIDC + c);
    float2 wb2 = *(const float2*)(Wb + 2 * HIDC + c);
    float part = ox * wb0.x + oy * wb0.y
               + r.x * wb1.x + r.y * wb1.y
               + (ox - r.x) * wb2.x + (oy - r.y) * wb2.y;
#pragma unroll
    for (int mk = 1; mk < 64; mk <<= 1) part += __shfl_xor(part, mk);
    float beta = 1.f / (1.f + __expf(-part));
    float2 rs = *(const float2*)(res + base);
    float tx = beta * r.x + (1.f - beta) * ox + rs.x;
    float ty = beta * r.y + (1.f - beta) * oy + rs.y;
    float sum = tx + ty;
#pragma unroll
    for (int mk = 1; mk < 64; mk <<= 1) sum += __shfl_xor(sum, mk);
    float mean = sum * (1.f / 128.f);
    float dx = tx - mean, dy = ty - mean;
    float vs = dx * dx + dy * dy;
#pragma unroll
    for (int mk = 1; mk < 64; mk <<= 1) vs += __shfl_xor(vs, mk);
    float rstd = 1.f / sqrtf(vs * (1.f / 128.f) + 1e-5f);
    float2 gg = *(const float2*)(g_ + c);
    float2 bb = *(const float2*)(b_ + c);
    float2 oo = make_float2(dx * rstd * gg.x + bb.x, dy * rstd * gg.y + bb.y);
    *(float2*)(out + base) = oo;
}

// ------------------------------ host launch ------------------------------
extern "C" void kernel_launch(void* const* d_in, const int* in_sizes, int n_in,
                              void* d_out, int out_size, void* d_ws, size_t ws_size,
                              hipStream_t stream) {
    const float* x    = (const float*)d_in[0];
    const int*   ei   = (const int*)d_in[1];
    const float* Wi   = (const float*)d_in[2];
    const float* bi   = (const float*)d_in[3];
    const float* Wq   = (const float*)d_in[4];
    const float* bq   = (const float*)d_in[5];
    const float* Wk   = (const float*)d_in[6];
    const float* bk   = (const float*)d_in[7];
    const float* Wv   = (const float*)d_in[8];
    const float* bv   = (const float*)d_in[9];
    const float* Ws_  = (const float*)d_in[10];
    const float* bs   = (const float*)d_in[11];
    const float* Wbeta= (const float*)d_in[12];
    const float* ln_g = (const float*)d_in[13];
    const float* ln_b = (const float*)d_in[14];
    const float* W1   = (const float*)d_in[15];
    const float* b1   = (const float*)d_in[16];
    const float* W2   = (const float*)d_in[17];
    const float* b2   = (const float*)d_in[18];
    const float* Wo   = (const float*)d_in[19];
    const float* bo   = (const float*)d_in[20];
    float* outp = (float*)d_out;

    const int Nn = in_sizes[0] / IN_C;   // 50000
    const int Ee = in_sizes[1] / 2;      // 600000
    const int* srcI = ei;
    const int* dstI = ei + Ee;

    // ws: h(1) | h2(1) | qh(0.5) | kv(1) | sb(1) [n128 units] | ints
    float* ws = (float*)d_ws;
    size_t n128 = (size_t)Nn * HIDC;
    float*     h   = ws;
    float*     h2  = h  + n128;
    _Float16*  qh  = (_Float16*)(h2 + n128);       // N*128 f16
    _Float16*  kv  = qh + (size_t)Nn * 128;        // N*256 f16
    float*     sb  = (float*)(kv + (size_t)Nn * 256);
    _Float16*  ffn = qh;                           // [N,512] f16 aliases qh|kv|sb
    int* rowptr = (int*)(sb + n128);
    int* cnt    = rowptr + (Nn + 1);
    int* csrc   = cnt + Nn;

    hipMemsetAsync(cnt, 0, Nn * sizeof(int), stream);
    count_deg_k<<<(Ee + 255) / 256, 256, 0, stream>>>(dstI, cnt, Ee);
    scan_k<<<1, 1024, 0, stream>>>(cnt, rowptr, Nn);
    hipMemsetAsync(cnt, 0, Nn * sizeof(int), stream);
    scatter_k<<<(Ee + 255) / 256, 256, 0, stream>>>(srcI, dstI, rowptr, cnt, csrc, Ee);

    const int mblk = (Nn + 127) / 128;   // 391
    dim3 blk(256);

    gemm_f16_k<1, false, false, float, float><<<dim3(1, mblk), blk, 0, stream>>>(x, Wi, bi, nullptr, h, Nn, HIDC, IN_C);

    int nwaveblk = (Nn + 3) / 4;

    for (int l = 0; l < LAYERS; ++l) {
        const float* Wq_l = Wq + (size_t)l * HIDC * HIDC;
        const float* Wk_l = Wk + (size_t)l * HIDC * HIDC;
        const float* Wv_l = Wv + (size_t)l * HIDC * HIDC;
        const float* Ws_l = Ws_ + (size_t)l * HIDC * HIDC;
        const float* bq_l = bq + (size_t)l * HIDC;
        const float* bk_l = bk + (size_t)l * HIDC;
        const float* bv_l = bv + (size_t)l * HIDC;
        const float* bs_l = bs + (size_t)l * HIDC;
        const float* Wb_l = Wbeta + (size_t)l * 3 * HIDC;
        const float* g_l  = ln_g + (size_t)l * HIDC;
        const float* b_l  = ln_b + (size_t)l * HIDC;
        const float* W1_l = W1 + (size_t)l * 4 * HIDC * HIDC;
        const float* b1_l = b1 + (size_t)l * 4 * HIDC;
        const float* W2_l = W2 + (size_t)l * HIDC * 4 * HIDC;
        const float* b2_l = b2 + (size_t)l * HIDC;

        qkvs_k<<<dim3(mblk), blk, 0, stream>>>(h, Wq_l, Wk_l, Wv_l, Ws_l,
                                               bq_l, bk_l, bv_l, bs_l,
                                               qh, kv, sb, Nn);

        attn_ln_k<<<nwaveblk, blk, 0, stream>>>(qh, kv, rowptr, csrc,
                                                sb, h, Wb_l, g_l, b_l, h2, Nn);

        gemm_f16_k<1, false, false, float, _Float16><<<dim3(4, mblk), blk, 0, stream>>>(h2, W1_l, b1_l, nullptr, ffn, Nn, 4 * HIDC, HIDC);
        gemm_f16_k<0, true, false, _Float16, float><<<dim3(1, mblk), blk, 0, stream>>>(ffn, W2_l, b2_l, h2, h, Nn, HIDC, 4 * HIDC);
    }

    gemm_f16_k<0, false, true, float, float><<<dim3(1, mblk), blk, 0, stream>>>(h, Wo, bo, nullptr, outp, Nn, OUT_C, HIDC);
}